// Round 2
// baseline (19249.751 us; speedup 1.0000x reference)
//
#include <hip/hip_runtime.h>
#include <hip/hip_bf16.h>
#include <math.h>

#define B_   2
#define L_   2048
#define DM   768
#define DI   1536
#define DS   16
#define DR   48
#define XZW  3072   // 2*DI
#define XDBW 80     // DR + 2*DS
#define NL   12
#define M_   (B_*L_)   // 4096

// ---------------------------------------------------------------------------
// Embedding gather: x[m,:] = emb[ids[m],:]
// ---------------------------------------------------------------------------
__global__ __launch_bounds__(256) void embed_kernel(
    const int* __restrict__ ids, const float* __restrict__ emb,
    float* __restrict__ x)
{
    const int m = blockIdx.x;
    const int id = ids[m];
    const float* src = emb + (size_t)id * DM;
    float* dst = x + (size_t)m * DM;
    for (int i = threadIdx.x; i < DM; i += 256) dst[i] = src[i];
}

// ---------------------------------------------------------------------------
// RMSNorm over last dim D (768): out = x * rsqrt(mean(x^2)+eps) * w
// one block per row
// ---------------------------------------------------------------------------
__global__ __launch_bounds__(256) void rmsnorm_kernel(
    const float* __restrict__ x, const float* __restrict__ w,
    float* __restrict__ out)
{
    const int m = blockIdx.x;
    const float* row = x + (size_t)m * DM;
    float ss = 0.f;
    for (int i = threadIdx.x; i < DM; i += 256) { float v = row[i]; ss = fmaf(v, v, ss); }
    #pragma unroll
    for (int o = 32; o > 0; o >>= 1) ss += __shfl_xor(ss, o);
    __shared__ float red[4];
    if ((threadIdx.x & 63) == 0) red[threadIdx.x >> 6] = ss;
    __syncthreads();
    const float total = red[0] + red[1] + red[2] + red[3];
    const float scale = rsqrtf(total / (float)DM + 1e-5f);
    for (int i = threadIdx.x; i < DM; i += 256)
        out[(size_t)m * DM + i] = row[i] * scale * w[i];
}

// ---------------------------------------------------------------------------
// Generic NT GEMM: C[m,n] = sum_k A[m,k]*Bw[n,k] (+ Res[m,n])
// A: MxK row-major, Bw: NxK row-major, C: MxN row-major.
// 128x128 tile, BK=16, 256 threads, 8x8 per-thread register tile.
// LDS read pattern: A/B fragments split tx*4 / 64+tx*4 -> max 2-way bank
// aliasing (free on CDNA4 per m136).
// ---------------------------------------------------------------------------
#define BM 128
#define BN 128
#define BK 16

__global__ __launch_bounds__(256) void gemm_nt(
    const float* __restrict__ A, const float* __restrict__ Bw,
    const float* __restrict__ Res, float* __restrict__ C,
    int M, int N, int K)
{
    __shared__ float As[BK][BM + 4];
    __shared__ float Bs[BK][BN + 4];
    const int m0 = blockIdx.x * BM;
    const int n0 = blockIdx.y * BN;
    const int tid = threadIdx.x;
    const int tx = tid & 15;       // 0..15 (cols)
    const int ty = tid >> 4;       // 0..15 (rows)
    const int lr = tid >> 2;       // 0..63 loader row
    const int lk = (tid & 3) << 2; // k-quad

    float acc[8][8];
    #pragma unroll
    for (int i = 0; i < 8; ++i)
        #pragma unroll
        for (int j = 0; j < 8; ++j) acc[i][j] = 0.f;

    for (int k0 = 0; k0 < K; k0 += BK) {
        #pragma unroll
        for (int p = 0; p < 2; ++p) {
            const int rowa = m0 + p * 64 + lr;
            float4 v = make_float4(0.f, 0.f, 0.f, 0.f);
            if (rowa < M) v = *(const float4*)(A + (size_t)rowa * K + (k0 + lk));
            As[lk + 0][p * 64 + lr] = v.x; As[lk + 1][p * 64 + lr] = v.y;
            As[lk + 2][p * 64 + lr] = v.z; As[lk + 3][p * 64 + lr] = v.w;
            const int rowb = n0 + p * 64 + lr;
            float4 u = make_float4(0.f, 0.f, 0.f, 0.f);
            if (rowb < N) u = *(const float4*)(Bw + (size_t)rowb * K + (k0 + lk));
            Bs[lk + 0][p * 64 + lr] = u.x; Bs[lk + 1][p * 64 + lr] = u.y;
            Bs[lk + 2][p * 64 + lr] = u.z; Bs[lk + 3][p * 64 + lr] = u.w;
        }
        __syncthreads();
        #pragma unroll
        for (int k = 0; k < BK; ++k) {
            float a[8], b[8];
            *(float4*)&a[0] = *(const float4*)&As[k][ty * 4];
            *(float4*)&a[4] = *(const float4*)&As[k][64 + ty * 4];
            *(float4*)&b[0] = *(const float4*)&Bs[k][tx * 4];
            *(float4*)&b[4] = *(const float4*)&Bs[k][64 + tx * 4];
            #pragma unroll
            for (int i = 0; i < 8; ++i)
                #pragma unroll
                for (int j = 0; j < 8; ++j) acc[i][j] = fmaf(a[i], b[j], acc[i][j]);
        }
        __syncthreads();
    }

    #pragma unroll
    for (int i = 0; i < 8; ++i) {
        const int row = m0 + (i < 4 ? ty * 4 + i : 64 + ty * 4 + i - 4);
        if (row >= M) continue;
        #pragma unroll
        for (int half = 0; half < 2; ++half) {
            const int col = n0 + half * 64 + tx * 4;
            if (col + 3 < N) {
                float4 v;
                v.x = acc[i][half * 4 + 0]; v.y = acc[i][half * 4 + 1];
                v.z = acc[i][half * 4 + 2]; v.w = acc[i][half * 4 + 3];
                if (Res) {
                    const float4 r = *(const float4*)(Res + (size_t)row * N + col);
                    v.x += r.x; v.y += r.y; v.z += r.z; v.w += r.w;
                }
                *(float4*)(C + (size_t)row * N + col) = v;
            } else {
                for (int j = 0; j < 4; ++j) {
                    const int c = col + j;
                    if (c < N) {
                        float v = acc[i][half * 4 + j];
                        if (Res) v += Res[(size_t)row * N + c];
                        C[(size_t)row * N + c] = v;
                    }
                }
            }
        }
    }
}

// ---------------------------------------------------------------------------
// Dedicated W_x GEMM: C[m,n] = sum_k A[m,k]*Bw[n,k], N=80 (full width per
// block), K=1536, BM=32, BK=32. Grid = M/32 = 128 blocks (vs 32 for the
// generic 128x128 kernel -> 4x better CU coverage).
// ---------------------------------------------------------------------------
#define WXBM 32
#define WXBK 32

__global__ __launch_bounds__(256) void gemm_wx(
    const float* __restrict__ A, const float* __restrict__ Bw,
    float* __restrict__ C)
{
    __shared__ float As[WXBK][WXBM + 2];
    __shared__ float Bs[WXBK][XDBW + 4];
    const int m0 = blockIdx.x * WXBM;
    const int tid = threadIdx.x;
    const int tx = tid & 15;      // col group: cols tx*4..+3 and 64+tx
    const int ty = tid >> 4;      // row group: rows ty*2, ty*2+1

    float acc[2][5] = {{0.f,0.f,0.f,0.f,0.f},{0.f,0.f,0.f,0.f,0.f}};

    for (int k0 = 0; k0 < DI; k0 += WXBK) {
        {   // A tile: 32 rows x 32 k = 1024 floats, one float4 per thread
            const int idx = tid * 4;
            const int ar = idx >> 5;
            const int ak = idx & 31;
            const float4 v = *(const float4*)(A + (size_t)(m0 + ar) * DI + k0 + ak);
            As[ak + 0][ar] = v.x; As[ak + 1][ar] = v.y;
            As[ak + 2][ar] = v.z; As[ak + 3][ar] = v.w;
        }
        // B tile: 80 rows x 32 k = 2560 floats
        for (int idx = tid * 4; idx < XDBW * WXBK; idx += 1024) {
            const int br = idx >> 5;
            const int bk = idx & 31;
            const float4 v = *(const float4*)(Bw + (size_t)br * DI + k0 + bk);
            Bs[bk + 0][br] = v.x; Bs[bk + 1][br] = v.y;
            Bs[bk + 2][br] = v.z; Bs[bk + 3][br] = v.w;
        }
        __syncthreads();
        #pragma unroll
        for (int k = 0; k < WXBK; ++k) {
            const float a0 = As[k][ty * 2];
            const float a1 = As[k][ty * 2 + 1];
            float b[5];
            *(float4*)&b[0] = *(const float4*)&Bs[k][tx * 4];
            b[4] = Bs[k][64 + tx];
            #pragma unroll
            for (int j = 0; j < 5; ++j) {
                acc[0][j] = fmaf(a0, b[j], acc[0][j]);
                acc[1][j] = fmaf(a1, b[j], acc[1][j]);
            }
        }
        __syncthreads();
    }

    #pragma unroll
    for (int i = 0; i < 2; ++i) {
        const int row = m0 + ty * 2 + i;
        float4 v = make_float4(acc[i][0], acc[i][1], acc[i][2], acc[i][3]);
        *(float4*)(C + (size_t)row * XDBW + tx * 4) = v;
        C[(size_t)row * XDBW + 64 + tx] = acc[i][4];
    }
}

// ---------------------------------------------------------------------------
// Causal depthwise conv (k=4, left-pad 3) + bias + silu.
// ---------------------------------------------------------------------------
__global__ __launch_bounds__(256) void conv_silu_kernel(
    const float* __restrict__ xz, const float* __restrict__ cw,
    const float* __restrict__ cb, float* __restrict__ xc)
{
    const int idx = blockIdx.x * 256 + threadIdx.x;   // (b*L+l)*DI + d
    const int d = idx % DI;
    const int r = idx / DI;       // b*L + l
    const int l = r % L_;
    const float* base = xz + (size_t)(r - l) * XZW + d;
    const float* w = cw + d * 4;
    float acc = cb[d];
    #pragma unroll
    for (int j = 0; j < 4; ++j) {
        const int ll = l - 3 + j;
        if (ll >= 0) acc = fmaf(w[j], base[(size_t)ll * XZW], acc);
    }
    xc[idx] = acc / (1.f + expf(-acc));   // silu
}

// ---------------------------------------------------------------------------
// dt[m,d] = softplus( xdb[m,0:48] . W_dt[d,:] + b_dt[d] )
// ---------------------------------------------------------------------------
__global__ __launch_bounds__(256) void dt_kernel(
    const float* __restrict__ xdb, const float* __restrict__ Wdt,
    const float* __restrict__ bdt, float* __restrict__ dtp)
{
    __shared__ float xr[DR];
    const int m = blockIdx.x;
    const int d = blockIdx.y * 256 + threadIdx.x;
    if (threadIdx.x < DR) xr[threadIdx.x] = xdb[(size_t)m * XDBW + threadIdx.x];
    __syncthreads();
    float acc = bdt[d];
    const float4* w = (const float4*)(Wdt + (size_t)d * DR);
    #pragma unroll
    for (int q = 0; q < DR / 4; ++q) {
        const float4 wv = w[q];
        acc = fmaf(wv.x, xr[q * 4 + 0], acc);
        acc = fmaf(wv.y, xr[q * 4 + 1], acc);
        acc = fmaf(wv.z, xr[q * 4 + 2], acc);
        acc = fmaf(wv.w, xr[q * 4 + 3], acc);
    }
    const float sp = fmaxf(acc, 0.f) + log1pf(expf(-fabsf(acc)));
    dtp[(size_t)m * DI + d] = sp;
}

// ---------------------------------------------------------------------------
// Selective scan. One 16-lane group per (b,d) channel, lane = state s.
// Chunk-stages dt/u/z/B/C through LDS (TC steps). Fuses +u*Dp and silu(z).
// ---------------------------------------------------------------------------
#define TC 64

__global__ __launch_bounds__(256) void scan_kernel(
    const float* __restrict__ u, const float* __restrict__ dtp,
    const float* __restrict__ xdb, const float* __restrict__ xz,
    const float* __restrict__ A_log, const float* __restrict__ Dp,
    float* __restrict__ y)
{
    __shared__ float dt_s[TC][16];
    __shared__ float u_s[TC][16];
    __shared__ float z_s[TC][16];
    __shared__ float bc_s[TC][32];
    __shared__ float y_s[TC][16];

    const int tid = threadIdx.x;
    const int g = tid >> 4;    // channel within block
    const int s = tid & 15;    // state index
    const int b = blockIdx.x / (DI / 16);
    const int d0 = (blockIdx.x % (DI / 16)) * 16;
    const int d = d0 + g;

    const float Ads = -expf(A_log[d0 * DS + tid]);  // A_log[(d0+g)*16 + s]
    const float Dv = Dp[d];
    float h = 0.f;

    const size_t rbase = (size_t)b * L_;
    const int jj = tid & 15, tt = tid >> 4;
    const int j32 = tid & 31, tt8 = tid >> 5;

    for (int t0 = 0; t0 < L_; t0 += TC) {
        __syncthreads();
        #pragma unroll
        for (int p = 0; p < 4; ++p) {
            const int t = tt + p * 16;
            const size_t r = rbase + t0 + t;
            dt_s[t][jj] = dtp[r * DI + d0 + jj];
            u_s[t][jj]  = u[r * DI + d0 + jj];
            z_s[t][jj]  = xz[r * XZW + DI + d0 + jj];
        }
        #pragma unroll
        for (int p = 0; p < 8; ++p) {
            const int t = tt8 + p * 8;
            const size_t r = rbase + t0 + t;
            bc_s[t][j32] = xdb[r * XDBW + DR + j32];
        }
        __syncthreads();
        #pragma unroll 4
        for (int t = 0; t < TC; ++t) {
            const float dtv = dt_s[t][g];
            const float uv  = u_s[t][g];
            const float Bv  = bc_s[t][s];
            const float Cv  = bc_s[t][16 + s];
            const float dA = __expf(dtv * Ads);
            h = fmaf(dA, h, dtv * Bv * uv);
            float p = h * Cv;
            p += __shfl_xor(p, 1);
            p += __shfl_xor(p, 2);
            p += __shfl_xor(p, 4);
            p += __shfl_xor(p, 8);
            if (s == 0) {
                const float zv = z_s[t][g];
                y_s[t][g] = (p + uv * Dv) * (zv / (1.f + __expf(-zv)));
            }
        }
        __syncthreads();   // FIX: y_s is produced by other waves — barrier
                           // before the cross-thread read below (was a race).
        #pragma unroll
        for (int p = 0; p < 4; ++p) {
            const int t = tt + p * 16;
            const size_t r = rbase + t0 + t;
            y[r * DI + d0 + jj] = y_s[t][jj];
        }
    }
}

// ---------------------------------------------------------------------------
extern "C" void kernel_launch(void* const* d_in, const int* in_sizes, int n_in,
                              void* d_out, int out_size, void* d_ws, size_t ws_size,
                              hipStream_t stream)
{
    const int*   ids      = (const int*)  d_in[0];
    const float* emb      = (const float*)d_in[1];
    const float* norm_w   = (const float*)d_in[2];
    const float* W_in     = (const float*)d_in[3];
    const float* conv_w   = (const float*)d_in[4];
    const float* conv_b   = (const float*)d_in[5];
    const float* W_x      = (const float*)d_in[6];
    const float* W_dt     = (const float*)d_in[7];
    const float* b_dt     = (const float*)d_in[8];
    const float* A_log    = (const float*)d_in[9];
    const float* Dp       = (const float*)d_in[10];
    const float* W_out    = (const float*)d_in[11];
    const float* norm_f_w = (const float*)d_in[12];
    float* out = (float*)d_out;

    float* ws  = (float*)d_ws;
    float* x   = ws;                      // M_ * DM
    float* xn  = x   + (size_t)M_ * DM;   // M_ * DM
    float* xz  = xn  + (size_t)M_ * DM;   // M_ * XZW
    float* xc  = xz  + (size_t)M_ * XZW;  // M_ * DI
    float* xdb = xc  + (size_t)M_ * DI;   // M_ * XDBW
    float* dtb = xdb + (size_t)M_ * XDBW; // M_ * DI
    float* yb  = dtb + (size_t)M_ * DI;   // M_ * DI

    embed_kernel<<<M_, 256, 0, stream>>>(ids, emb, x);

    for (int i = 0; i < NL; ++i) {
        rmsnorm_kernel<<<M_, 256, 0, stream>>>(x, norm_w + (size_t)i * DM, xn);
        gemm_nt<<<dim3(M_ / BM, XZW / BN), 256, 0, stream>>>(
            xn, W_in + (size_t)i * XZW * DM, nullptr, xz, M_, XZW, DM);
        conv_silu_kernel<<<(M_ * DI) / 256, 256, 0, stream>>>(
            xz, conv_w + (size_t)i * DI * 4, conv_b + (size_t)i * DI, xc);
        gemm_wx<<<M_ / WXBM, 256, 0, stream>>>(
            xc, W_x + (size_t)i * XDBW * DI, xdb);
        dt_kernel<<<dim3(M_, DI / 256), 256, 0, stream>>>(
            xdb, W_dt + (size_t)i * DI * DR, b_dt + (size_t)i * DI, dtb);
        scan_kernel<<<(B_ * DI) / 16, 256, 0, stream>>>(
            xc, dtb, xdb, xz, A_log + (size_t)i * DI * DS, Dp + (size_t)i * DI, yb);
        gemm_nt<<<dim3(M_ / BM, DM / BN), 256, 0, stream>>>(
            yb, W_out + (size_t)i * DM * DI, x, x, M_, DM, DI);
    }

    rmsnorm_kernel<<<M_, 256, 0, stream>>>(x, norm_f_w, xn);
    gemm_nt<<<dim3(M_ / BM, (50257 + BN - 1) / BN), 256, 0, stream>>>(
        xn, emb, nullptr, out, M_, 50257, DM);
}